// Round 7
// baseline (61.479 us; speedup 1.0000x reference)
//
#include <hip/hip_runtime.h>
#include <stdint.h>

// Detection post-processor, SINGLE fused kernel (80 blocks):
//   phase 1: coalesced grid-stride score scan -> per-class key lists (ws)
//   grid sync (arrive counter; all 80 blocks co-resident on 256 CUs)
//   phase 2: per-class rank-sort + adjacency-mask greedy NMS (+ global
//            histogram built during emission)
//   phase 3: last block to finish runs the global top-100.
// N=2048 proposals, C=81 classes (class 0 dropped).
// Inputs:  d_in[0] = boxes  [2048, 324] f32, d_in[1] = scores [2048, 81] f32
// Output:  d_out = [100, 6] f32 (x1,y1,x2,y2,score,label)
// Workspace (191232 B <= 192000; [0,21632) zeroed per call by memset node):
//   [0]      u32 syncArr          grid-sync arrive counter
//   [64]     u32 gdone            NMS-done counter
//   [128]    u32 cnt[80*16]       padded per-class candidate counters
//   [5248]   u32 ghist[4096]      global score histogram (built at emission)
//   [21632]  u64 keyws[80*190]    per-class candidate keys
//   [143232] f32 sarr[8000]       per-(class,rank) score (NEGINF pad)
//   [175232] u16 sidx[8000]       proposal index of each kept det

#define NPROP   2048
#define NCLS    81
#define SCORE_T 0.05f
#define NMS_T   0.5f
#define PERCLS  100
#define NREC    (80 * PERCLS)   // 8000
#define NEGINF  -1.0e9f
#define NBIN    4096
#define SELCAP  4096
#define MCAP    190             // fast-path candidate cap per class
#define NMSBLK  80

typedef unsigned long long u64;
typedef unsigned int u32;
typedef unsigned short u16;

__device__ __forceinline__ u32 fflip(float f) {
  u32 u = __float_as_uint(f);
  return (u & 0x80000000u) ? ~u : (u | 0x80000000u);
}
__device__ __forceinline__ float funflip(u32 u) {
  u32 v = (u & 0x80000000u) ? (u ^ 0x80000000u) : ~u;
  return __uint_as_float(v);
}
__device__ __forceinline__ float4 clip_box(float4 r) {
  float4 b;
  b.x = fminf(fmaxf(r.x, 0.f), 1332.f);
  b.y = fminf(fmaxf(r.y, 0.f), 799.f);
  b.z = fminf(fmaxf(r.z, 0.f), 1332.f);
  b.w = fminf(fmaxf(r.w, 0.f), 799.f);
  return b;
}
// Reference IoU (exact expression; symmetric and f32-commutative).
__device__ __forceinline__ float iou_ref(float4 a, float aarea, float4 b,
                                         float barea) {
  float ix1 = fmaxf(a.x, b.x), iy1 = fmaxf(a.y, b.y);
  float ix2 = fminf(a.z, b.z), iy2 = fminf(a.w, b.w);
  float inter = fmaxf(ix2 - ix1, 0.f) * fmaxf(iy2 - iy1, 0.f);
  return inter / (aarea + barea - inter + 1e-9f);
}

// Key: [63:32] fflip(score), [31:0] ~proposal_idx. Descending key order ==
// (score desc, idx asc) == the reference's stable argsort(-s_masked). Unique.

__global__ __launch_bounds__(256) void fused_kernel(
    const float* __restrict__ boxes, const float* __restrict__ scores,
    u32* __restrict__ syncArr, u32* __restrict__ gdone,
    u32* __restrict__ cnt, u32* __restrict__ ghist,
    u64* __restrict__ keyws, float* __restrict__ sarr, u16* __restrict__ sidx,
    float* __restrict__ out) {
  __shared__ __align__(16) char arena[50176];
  u64*    keysLds  = (u64*)arena;                   // [2048] 16384 B (slow path)
  u64*    sortedA  = (u64*)(arena + 16384);         // [190]   1520 B
  float4* bxR      = (float4*)(arena + 17920);      // [190]   3040 B rank-idx
  float4* keptBx   = (float4*)(arena + 20992);      // [100]   1600 B
  float*  keptArea = (float*)(arena + 22592);       // [100]    400 B
  float4* bxC      = (float4*)(arena + 23040);      // [64]    1024 B chunk stage
  // --- topk overlay (last block only, after NMS emission is done) ---
  u32*    hist     = (u32*)arena;                   // [4096] 16384 B
  u64*    sel      = (u64*)(arena + 16384);         // [4096] 32768 B
  u64*    selSorted= (u64*)(arena + 49152);         // [128]   1024 B

  __shared__ int mcount, kkOut, lastOld, selCount;
  __shared__ volatile int sC, sB;
  __shared__ volatile u32 sNeed;

  const int tid = threadIdx.x;
  const int c = blockIdx.x + 1;                     // class 1..80
  const int cls = c - 1;

  // ---- Phase 1: coalesced score scan (grid-stride over 41472 float4s) ----
  const float4* scores4 = (const float4*)scores;
  for (int g = blockIdx.x * 256 + tid; g < (NPROP * NCLS) / 4;
       g += NMSBLK * 256) {
    const float4 s4 = scores4[g];
    const int flat = g * 4;
    #pragma unroll
    for (int t = 0; t < 4; ++t) {
      float s = (t == 0) ? s4.x : (t == 1) ? s4.y : (t == 2) ? s4.z : s4.w;
      int f = flat + t;
      int i = f / 81;
      int cc = f - i * 81;
      if (cc != 0 && s > SCORE_T) {
        int slot = (int)atomicAdd(&cnt[(cc - 1) * 16], 1u);
        if (slot < MCAP)
          keyws[(cc - 1) * MCAP + slot] = ((u64)fflip(s) << 32) | (u32)(~(u32)i);
      }
    }
  }

  // ---- Grid sync: 80 blocks, all co-resident (80 <= 256 CUs) ----
  __syncthreads();
  if (tid == 0) {
    __threadfence();
    atomicAdd(syncArr, 1u);
    while (__hip_atomic_load(syncArr, __ATOMIC_RELAXED,
                             __HIP_MEMORY_SCOPE_AGENT) < (u32)NMSBLK)
      __builtin_amdgcn_s_sleep(16);
    __threadfence();
    sC = 0; sNeed = 1; sB = 0;            // safe defaults for topk
  }
  __syncthreads();

  // ---- Phase 2: per-class sort + NMS ----
  // Overlapped loads: cnt, keys, and key-dependent box gather all in flight
  // together (box address masked so garbage keys stay in-bounds).
  const int M0 = (int)cnt[cls * 16];
  u64 kr = 0ULL;
  float4 raw = make_float4(0.f, 0.f, 0.f, 0.f);
  if (tid < MCAP) {
    kr = keyws[cls * MCAP + tid];
    u32 pi = (~(u32)kr) & (NPROP - 1);    // masked: safe even for stale slots
    raw = *(const float4*)(boxes + (size_t)pi * (NCLS * 4) + c * 4);
  }
  const bool fast = (M0 <= MCAP);
  int M;

  if (fast) {
    M = M0;
    if (tid < M) keysLds[tid] = kr;
    __syncthreads();
    if (tid < M) {
      int rk = 0;
      for (int j = 0; j < M; ++j) rk += (keysLds[j] > kr) ? 1 : 0;
      sortedA[rk] = kr;
      bxR[rk] = clip_box(raw);            // direct place at own rank
    }
    __syncthreads();
  } else {
    // Slow fallback (correctness only; keyws contents ignored):
    // strided rescan + block bitonic sort.
    if (tid == 0) mcount = 0;
    __syncthreads();
    for (int i = tid; i < NPROP; i += 256) {
      float s = scores[i * NCLS + c];
      if (s > SCORE_T) {
        int slot = atomicAdd(&mcount, 1);
        keysLds[slot] = ((u64)fflip(s) << 32) | (u32)(~(u32)i);
      }
    }
    __syncthreads();
    M = mcount;
    int P = 256; while (P < M) P <<= 1;
    for (int i = M + tid; i < P; i += 256) keysLds[i] = 0ULL;
    __syncthreads();
    for (int k = 2; k <= P; k <<= 1) {
      for (int j = k >> 1; j > 0; j >>= 1) {
        for (int i = tid; i < P; i += 256) {
          int ixj = i ^ j;
          if (ixj > i) {
            u64 a = keysLds[i], b = keysLds[ixj];
            if (((i & k) == 0) ? (a < b) : (a > b)) { keysLds[i] = b; keysLds[ixj] = a; }
          }
        }
        __syncthreads();
      }
    }
  }
  const u64* SK = fast ? sortedA : keysLds;

  float* sbase = sarr + cls * PERCLS;
  u16* ibase = sidx + cls * PERCLS;

  // Greedy NMS, adjacency-mask form (wave 0 only). Semantics identical to
  // greedy: a candidate dies iff an earlier KEPT candidate has IoU > thresh.
  if (tid < 64) {
    const int lane = tid;
    int kkTot = 0;
    const int NC = (M + 63) >> 6;
    for (int q = 0; q < NC && kkTot < PERCLS; ++q) {
      const int cbase = q << 6;
      const int ccnt = min(64, M - cbase);
      u64 mykey = 0ULL;
      float4 b = make_float4(0.f, 0.f, 0.f, 0.f);
      int alive = 0;
      if (lane < ccnt) {
        mykey = SK[cbase + lane];
        if (fast) {
          b = bxR[cbase + lane];
        } else {
          u32 pi = ~(u32)mykey;
          b = clip_box(*(const float4*)(boxes + (size_t)pi * (NCLS * 4) + c * 4));
        }
        alive = 1;
      }
      bxC[lane] = b;                       // stage chunk boxes (wave-sync)
      const float barea = fmaxf(b.z - b.x, 0.f) * fmaxf(b.w - b.y, 0.f);
      __builtin_amdgcn_wave_barrier();

      // (0) cross-chunk: dead if any already-kept box overlaps me.
      for (int t = 0; t < kkTot; ++t) {
        float4 kb = keptBx[t];
        if (iou_ref(kb, keptArea[t], b, barea) > NMS_T) alive = 0;
      }

      // (a) intra-chunk suppression row: bits j > lane with IoU > thresh.
      u64 supRow = 0ULL;
      for (int j = 0; j < ccnt; ++j) {
        float4 ob = bxC[j];                // LDS broadcast
        float oarea = fmaxf(ob.z - ob.x, 0.f) * fmaxf(ob.w - ob.y, 0.f);
        bool hit = (j > lane) && (iou_ref(b, barea, ob, oarea) > NMS_T);
        supRow |= (u64)(hit ? 1u : 0u) << j;
      }
      const u32 rowLo = (u32)supRow, rowHi = (u32)(supRow >> 32);

      // (b) scalar propagation over alive candidates in rank order.
      u64 work = __ballot(alive != 0);
      u64 kept = 0ULL;
      while (work) {
        int i = (int)__builtin_ctzll(work);
        u32 rl = __builtin_amdgcn_readlane(rowLo, i);
        u32 rh = __builtin_amdgcn_readlane(rowHi, i);
        kept |= 1ull << i;
        work &= ~(((u64)rh << 32) | rl);
        work &= work - 1;                  // clear bit i
      }

      // cap at PERCLS kept per class (trim highest ranks; then we stop).
      int budget = PERCLS - kkTot;
      int over = (int)__popcll(kept) - budget;
      while (over-- > 0) kept &= ~(1ull << (63 - __builtin_clzll(kept)));

      // (c) parallel emission in rank order + global histogram contribution.
      if ((kept >> lane) & 1ull) {
        int rank = kkTot + (int)__popcll(kept & ((1ull << lane) - 1ull));
        u32 k32 = (u32)(mykey >> 32);
        sbase[rank] = funflip(k32);
        ibase[rank] = (u16)(~(u32)mykey);
        keptBx[rank] = b;
        keptArea[rank] = barea;
        // bucket = bits [26:15]; all kept scores are in (0.05,1] -> top 5
        // bits of fflip are 0b10111, so bucket order == score order.
        if ((k32 >> 27) == 0x17u) atomicAdd(&ghist[(k32 >> 15) & 0xFFFu], 1u);
      }
      kkTot += (int)__popcll(kept);
      __builtin_amdgcn_wave_barrier();
    }
    if (lane == 0) kkOut = kkTot;
  }
  __syncthreads();

  // Pad remaining slots (pads never reach the top-100 for this workload).
  for (int slot = kkOut + tid; slot < PERCLS; slot += 256) {
    sbase[slot] = NEGINF;
    ibase[slot] = 0;
  }

  // ---- Phase 3: last block to finish runs the global top-100 ----
  __threadfence();          // release this block's sarr/sidx/ghist stores
  __syncthreads();
  if (tid == 0) lastOld = (int)atomicAdd(gdone, 1u);   // device-scope
  __syncthreads();
  if (lastOld != NMSBLK - 1) return;
  __threadfence();          // acquire: see all other blocks' stores

  // Histogram was built during emission: just copy to LDS.
  for (int b = tid; b < NBIN; b += 256) hist[b] = ghist[b];
  if (tid == 0) selCount = 0;
  if (tid < 128) selSorted[tid] = 0ULL;
  __syncthreads();

  // Wave 0: find bucket B containing the 100th-largest score.
  if (tid < 64) {
    const int lane = tid;
    u32 p = 0;
    for (int t = 0; t < 64; ++t) p += hist[lane * 64 + t];
    u32 S = p;                               // inclusive suffix over chunks
    for (int off = 1; off < 64; off <<= 1) {
      u32 v = __shfl_down(S, off, 64);
      if (lane + off < 64) S += v;
    }
    u32 Sn = __shfl_down(S, 1, 64);
    if (lane == 63) Sn = 0;
    if (S >= 100u && Sn < 100u) { sC = lane; sNeed = 100u - Sn; }
    __builtin_amdgcn_wave_barrier();
    const int C = sC;
    const u32 need2 = sNeed;
    u32 T = hist[C * 64 + lane];             // inclusive suffix over bins
    for (int off = 1; off < 64; off <<= 1) {
      u32 v = __shfl_down(T, off, 64);
      if (lane + off < 64) T += v;
    }
    u32 Tn = __shfl_down(T, 1, 64);
    if (lane == 63) Tn = 0;
    if (T >= need2 && Tn < need2) sB = C * 64 + lane;
    __builtin_amdgcn_wave_barrier();
  }
  __syncthreads();
  const int B = sB;

  // Compact entries with bucket >= B (>=100 by construction, typically ~150).
  const float4* s4p = (const float4*)sarr;
  for (int e4 = tid; e4 < NREC / 4; e4 += 256) {
    float4 s4 = s4p[e4];
    #pragma unroll
    for (int t = 0; t < 4; ++t) {
      float sv = (t == 0) ? s4.x : (t == 1) ? s4.y : (t == 2) ? s4.z : s4.w;
      u32 k32 = fflip(sv);
      if ((k32 >> 27) == 0x17u && (int)((k32 >> 15) & 0xFFFu) >= B) {
        int slot = atomicAdd(&selCount, 1);
        int e = e4 * 4 + t;
        if (slot < SELCAP) sel[slot] = ((u64)k32 << 32) | (u32)(~(u32)e);
      }
    }
  }
  __syncthreads();
  const int CB = min(selCount, SELCAP);

  // Rank-select the top 100 (keys unique via ~e; tie order == lowest flat
  // index first, matching lax.top_k — (class, rank) lex order is preserved).
  for (int r = tid; r < CB; r += 256) {
    u64 kr2 = sel[r];
    int rk = 0;
    for (int j = 0; j < CB; ++j) rk += (sel[j] > kr2) ? 1 : 0;
    if (rk < PERCLS) selSorted[rk] = kr2;
  }
  __syncthreads();

  if (tid < PERCLS) {
    u64 key = selSorted[tid];
    u32 e = ~(u32)key;
    float* o = out + tid * 6;
    if (key != 0ULL && e < NREC) {
      int wc = (int)(e / PERCLS) + 1;        // class label from entry index
      u32 pi = sidx[e];
      // Re-gather + re-clip the winner's box (bitwise-identical clip).
      float4 b = clip_box(*(const float4*)(boxes + (size_t)pi * (NCLS * 4) + wc * 4));
      o[0] = b.x; o[1] = b.y; o[2] = b.z; o[3] = b.w;
      o[4] = funflip((u32)(key >> 32));
      o[5] = (float)wc;
    } else {
      // only reachable if fewer than 100 detections survive globally
      o[0] = 0.f; o[1] = 0.f; o[2] = 0.f; o[3] = 0.f; o[4] = NEGINF; o[5] = 0.f;
    }
  }
}

extern "C" void kernel_launch(void* const* d_in, const int* in_sizes, int n_in,
                              void* d_out, int out_size, void* d_ws, size_t ws_size,
                              hipStream_t stream) {
  const float* boxes  = (const float*)d_in[0];   // [2048, 324]
  const float* scores = (const float*)d_in[1];   // [2048, 81]
  char* ws = (char*)d_ws;
  u32*  syncArr = (u32*)ws;                      // [0,64)
  u32*  gdone   = (u32*)(ws + 64);               // [64,128)
  u32*  cnt     = (u32*)(ws + 128);              // [128, 5248)
  u32*  ghist   = (u32*)(ws + 5248);             // [5248, 21632)
  u64*  keyws   = (u64*)(ws + 21632);            // [21632, 143232)
  float* sarr   = (float*)(ws + 143232);         // [143232, 175232)
  u16*  sidx    = (u16*)(ws + 175232);           // [175232, 191232)
  float* out    = (float*)d_out;                 // [100, 6]

  hipMemsetAsync(ws, 0, 21632, stream);          // zero sync ctrs + cnt + ghist
  fused_kernel<<<NMSBLK, 256, 0, stream>>>(boxes, scores, syncArr, gdone,
                                           cnt, ghist, keyws, sarr, sidx, out);
}

// Round 8
// 59.839 us; speedup vs baseline: 1.0274x; 1.0274x over previous
//
#include <hip/hip_runtime.h>
#include <stdint.h>

// Detection post-processor, two kernels:
//  K1: coalesced score scan -> per-class candidate key lists (ws)
//  K2: per-class rank-sort + adjacency-mask greedy NMS (+ global histogram
//      built at emission); last-finishing block runs the global top-100.
// N=2048 proposals, C=81 classes (class 0 dropped).
// Inputs:  d_in[0] = boxes  [2048, 324] f32, d_in[1] = scores [2048, 81] f32
// Output:  d_out = [100, 6] f32 (x1,y1,x2,y2,score,label)
// Workspace (190016 B <= 192000; [0,13376) zeroed per call by memset node):
//   [0]      u32 gdone            NMS-done counter
//   [64]     u32 cnt[80*16]       padded per-class candidate counters
//   [5184]   u32 ghist[2048]      global kept-score histogram
//   [13376]  u64 keyws[80*176]    per-class candidate keys
//   [126016] u64 psarr[8000]      per-(class,rank) packed (k32,cls,pi)

#define NPROP   2048
#define NCLS    81
#define SCORE_T 0.05f
#define NMS_T   0.5f
#define PERCLS  100
#define NREC    (80 * PERCLS)   // 8000
#define NEGINF  -1.0e9f
#define NBIN    2048
#define SELCAP  4096
#define MCAP    176             // fast-path candidate cap per class

typedef unsigned long long u64;
typedef unsigned int u32;

__device__ __forceinline__ u32 fflip(float f) {
  u32 u = __float_as_uint(f);
  return (u & 0x80000000u) ? ~u : (u | 0x80000000u);
}
__device__ __forceinline__ float funflip(u32 u) {
  u32 v = (u & 0x80000000u) ? (u ^ 0x80000000u) : ~u;
  return __uint_as_float(v);
}
__device__ __forceinline__ float4 clip_box(float4 r) {
  float4 b;
  b.x = fminf(fmaxf(r.x, 0.f), 1332.f);
  b.y = fminf(fmaxf(r.y, 0.f), 799.f);
  b.z = fminf(fmaxf(r.z, 0.f), 1332.f);
  b.w = fminf(fmaxf(r.w, 0.f), 799.f);
  return b;
}
// Reference IoU (exact expression; symmetric and f32-commutative).
__device__ __forceinline__ float iou_ref(float4 a, float aarea, float4 b,
                                         float barea) {
  float ix1 = fmaxf(a.x, b.x), iy1 = fmaxf(a.y, b.y);
  float ix2 = fminf(a.z, b.z), iy2 = fminf(a.w, b.w);
  float inter = fmaxf(ix2 - ix1, 0.f) * fmaxf(iy2 - iy1, 0.f);
  return inter / (aarea + barea - inter + 1e-9f);
}

// Sort key: [63:32] fflip(score), [31:0] ~proposal_idx. Descending order ==
// (score desc, idx asc) == the reference's stable argsort(-s_masked). Unique.
// Packed record: [63:32] fflip(score), [17:11] 79-cls, [10:0] 2047-pi.
// Descending order == (score desc, cls asc, pi asc) == lax.top_k tie order
// (lowest flat index first; within a class, equal scores sort by idx asc).

// ---- Kernel 1: coalesced scan. 162 blocks x 256 thr, 1 float4/thread. ----
__global__ __launch_bounds__(256) void scan_kernel(
    const float4* __restrict__ scores4, u32* __restrict__ cnt,
    u64* __restrict__ keyws) {
  const int g = blockIdx.x * 256 + threadIdx.x;   // 41472 = 2048*81/4 exactly
  const float4 s4 = scores4[g];
  const int flat = g * 4;
  #pragma unroll
  for (int t = 0; t < 4; ++t) {
    float s = (t == 0) ? s4.x : (t == 1) ? s4.y : (t == 2) ? s4.z : s4.w;
    int f = flat + t;
    int i = f / 81;
    int c = f - i * 81;
    if (c != 0 && s > SCORE_T) {
      int cls = c - 1;
      int slot = (int)atomicAdd(&cnt[cls * 16], 1u);
      if (slot < MCAP)
        keyws[cls * MCAP + slot] = ((u64)fflip(s) << 32) | (u32)(~(u32)i);
    }
  }
}

// ---- Kernel 2: per-class sort + mask-NMS; last block runs global top-100.
__global__ __launch_bounds__(256) void nms_topk_kernel(
    const float* __restrict__ boxes, const float* __restrict__ scores,
    const u32* __restrict__ cnt, const u64* __restrict__ keyws,
    u64* __restrict__ psarr, u32* __restrict__ ghist,
    u32* __restrict__ gdone, float* __restrict__ out) {
  __shared__ __align__(16) char arena[50176];
  u64*    keysLds  = (u64*)arena;                   // [2048] 16384 B (slow path)
  u64*    sortedA  = (u64*)(arena + 16384);         // [176]   1408 B
  float4* bxR      = (float4*)(arena + 17920);      // [176]   2816 B rank-idx
  float4* keptBx   = (float4*)(arena + 20992);      // [100]   1600 B
  float*  keptArea = (float*)(arena + 22592);       // [100]    400 B
  float4* bxC      = (float4*)(arena + 23040);      // [64]    1024 B chunk stage
  // --- topk overlay (last block only, after NMS emission is done) ---
  u32*    hist     = (u32*)arena;                   // [2048]  8192 B
  u64*    sel      = (u64*)(arena + 16384);         // [4096] 32768 B
  u64*    selSorted= (u64*)(arena + 49152);         // [128]   1024 B

  __shared__ int mcount, kkOut, lastOld, selCount;
  __shared__ volatile int sC, sB;
  __shared__ volatile u32 sNeed;

  const int tid = threadIdx.x;
  const int c = blockIdx.x + 1;                     // class 1..80
  const int cls = c - 1;

  // Overlapped head loads: keys + masked key-dependent box gather issue
  // concurrently with the cnt load (no serial cnt->keys->boxes chain).
  u64 kr = 0ULL;
  float4 raw = make_float4(0.f, 0.f, 0.f, 0.f);
  if (tid < MCAP) {
    kr = keyws[cls * MCAP + tid];
    u32 pi = (~(u32)kr) & (NPROP - 1);    // masked: safe even for stale slots
    raw = *(const float4*)(boxes + (size_t)pi * (NCLS * 4) + c * 4);
  }
  const int M0 = (int)cnt[cls * 16];
  const bool fast = (M0 <= MCAP);
  int M;

  if (fast) {
    M = M0;
    if (tid < M) keysLds[tid] = kr;
    __syncthreads();
    if (tid < M) {
      int rk = 0;
      for (int j = 0; j < M; ++j) rk += (keysLds[j] > kr) ? 1 : 0;
      sortedA[rk] = kr;
      bxR[rk] = clip_box(raw);            // direct place at own rank
    }
    __syncthreads();
  } else {
    // Slow fallback (correctness only; keyws contents ignored):
    // strided rescan + block bitonic sort.
    if (tid == 0) mcount = 0;
    __syncthreads();
    for (int i = tid; i < NPROP; i += 256) {
      float s = scores[i * NCLS + c];
      if (s > SCORE_T) {
        int slot = atomicAdd(&mcount, 1);
        keysLds[slot] = ((u64)fflip(s) << 32) | (u32)(~(u32)i);
      }
    }
    __syncthreads();
    M = mcount;
    int P = 256; while (P < M) P <<= 1;
    for (int i = M + tid; i < P; i += 256) keysLds[i] = 0ULL;
    __syncthreads();
    for (int k = 2; k <= P; k <<= 1) {
      for (int j = k >> 1; j > 0; j >>= 1) {
        for (int i = tid; i < P; i += 256) {
          int ixj = i ^ j;
          if (ixj > i) {
            u64 a = keysLds[i], b = keysLds[ixj];
            if (((i & k) == 0) ? (a < b) : (a > b)) { keysLds[i] = b; keysLds[ixj] = a; }
          }
        }
        __syncthreads();
      }
    }
  }
  const u64* SK = fast ? sortedA : keysLds;

  u64* pbase = psarr + cls * PERCLS;

  // ---- Greedy NMS, adjacency-mask form (wave 0 only). Semantics identical
  // to greedy: a candidate dies iff an earlier KEPT candidate has IoU>thresh.
  if (tid < 64) {
    const int lane = tid;
    int kkTot = 0;
    const int NC = (M + 63) >> 6;
    for (int q = 0; q < NC && kkTot < PERCLS; ++q) {
      const int cbase = q << 6;
      const int ccnt = min(64, M - cbase);
      u64 mykey = 0ULL;
      float4 b = make_float4(0.f, 0.f, 0.f, 0.f);
      int alive = 0;
      if (lane < ccnt) {
        mykey = SK[cbase + lane];
        if (fast) {
          b = bxR[cbase + lane];
        } else {
          u32 pi = ~(u32)mykey;
          b = clip_box(*(const float4*)(boxes + (size_t)pi * (NCLS * 4) + c * 4));
        }
        alive = 1;
      }
      bxC[lane] = b;                       // stage chunk boxes (wave-sync)
      const float barea = fmaxf(b.z - b.x, 0.f) * fmaxf(b.w - b.y, 0.f);
      __builtin_amdgcn_wave_barrier();

      // (0) cross-chunk: dead if any already-kept box overlaps me.
      for (int t = 0; t < kkTot; ++t) {
        float4 kb = keptBx[t];
        if (iou_ref(kb, keptArea[t], b, barea) > NMS_T) alive = 0;
      }

      // (a) intra-chunk suppression row: bits j > lane with IoU > thresh.
      u64 supRow = 0ULL;
      for (int j = 0; j < ccnt; ++j) {
        float4 ob = bxC[j];                // LDS broadcast
        float oarea = fmaxf(ob.z - ob.x, 0.f) * fmaxf(ob.w - ob.y, 0.f);
        bool hit = (j > lane) && (iou_ref(b, barea, ob, oarea) > NMS_T);
        supRow |= (u64)(hit ? 1u : 0u) << j;
      }
      const u32 rowLo = (u32)supRow, rowHi = (u32)(supRow >> 32);

      // (b) scalar propagation over alive candidates in rank order.
      u64 work = __ballot(alive != 0);
      u64 kept = 0ULL;
      while (work) {
        int i = (int)__builtin_ctzll(work);
        u32 rl = __builtin_amdgcn_readlane(rowLo, i);
        u32 rh = __builtin_amdgcn_readlane(rowHi, i);
        kept |= 1ull << i;
        work &= ~(((u64)rh << 32) | rl);
        work &= work - 1;                  // clear bit i
      }

      // cap at PERCLS kept per class (trim highest ranks; then we stop).
      int budget = PERCLS - kkTot;
      int over = (int)__popcll(kept) - budget;
      while (over-- > 0) kept &= ~(1ull << (63 - __builtin_clzll(kept)));

      // (c) parallel emission: packed record + global histogram (the ghist
      // atomics drain in the same vmcnt as the psarr stores -> free).
      if ((kept >> lane) & 1ull) {
        int rank = kkTot + (int)__popcll(kept & ((1ull << lane) - 1ull));
        u32 k32 = (u32)(mykey >> 32);
        // low 11 bits of mykey == 2047 - pi  (mykey[31:0] = ~pi, pi < 2048)
        pbase[rank] = ((u64)k32 << 32) | ((u64)(u32)(79 - cls) << 11) |
                      (u64)((u32)mykey & 0x7FFu);
        keptBx[rank] = b;
        keptArea[rank] = barea;
        // bucket = bits [26:16]; kept scores in (0.05,1] share fflip top 5
        // bits (0b10111) so bucket order == score order.
        atomicAdd(&ghist[(k32 >> 16) & 0x7FFu], 1u);
      }
      kkTot += (int)__popcll(kept);
      __builtin_amdgcn_wave_barrier();
    }
    if (lane == 0) kkOut = kkTot;
  }
  __syncthreads();

  // Pad remaining slots (pads never reach the top-100 for this workload).
  for (int slot = kkOut + tid; slot < PERCLS; slot += 256) pbase[slot] = 0ULL;

  // ---- Last block to finish runs the global top-100 ----
  __threadfence();          // release this block's psarr/ghist stores
  __syncthreads();
  if (tid == 0) lastOld = (int)atomicAdd(gdone, 1u);   // device-scope
  __syncthreads();
  if (lastOld != 79) return;
  __threadfence();          // acquire: see all other blocks' stores

  // Histogram was built during emission: just copy to LDS.
  for (int b = tid; b < NBIN; b += 256) hist[b] = ghist[b];
  if (tid == 0) { selCount = 0; sC = 0; sNeed = 1; sB = 0; }
  if (tid < 128) selSorted[tid] = 0ULL;
  __syncthreads();

  // Wave 0: find bucket B containing the 100th-largest kept score.
  if (tid < 64) {
    const int lane = tid;
    u32 p = 0;
    for (int t = 0; t < 32; ++t) p += hist[lane * 32 + t];
    u32 S = p;                               // inclusive suffix over chunks
    for (int off = 1; off < 64; off <<= 1) {
      u32 v = __shfl_down(S, off, 64);
      if (lane + off < 64) S += v;
    }
    u32 Sn = __shfl_down(S, 1, 64);
    if (lane == 63) Sn = 0;
    if (S >= 100u && Sn < 100u) { sC = lane; sNeed = 100u - Sn; }
    __builtin_amdgcn_wave_barrier();
    const int C = sC;
    const u32 need2 = sNeed;
    u32 T = (lane < 32) ? hist[C * 32 + lane] : 0;   // suffix over 32 bins
    for (int off = 1; off < 64; off <<= 1) {
      u32 v = __shfl_down(T, off, 64);
      if (lane + off < 64) T += v;
    }
    u32 Tn = __shfl_down(T, 1, 64);
    if (lane == 63) Tn = 0;
    if (lane < 32 && T >= need2 && Tn < need2) sB = C * 32 + lane;
    __builtin_amdgcn_wave_barrier();
  }
  __syncthreads();
  const int B = sB;

  // Compact packed records with bucket >= B (>=100 by construction when >=100
  // kept exist; typically ~110-150 entries).
  for (int e = tid; e < NREC; e += 256) {
    u64 pk = psarr[e];
    u32 k32 = (u32)(pk >> 32);
    if ((k32 >> 27) == 0x17u && (int)((k32 >> 16) & 0x7FFu) >= B) {
      int slot = atomicAdd(&selCount, 1);
      if (slot < SELCAP) sel[slot] = pk;
    }
  }
  __syncthreads();
  const int CB = min(selCount, SELCAP);

  // Rank-select the top 100 (packed keys unique; descending order == score
  // desc, then lowest flat index — matching lax.top_k).
  for (int r = tid; r < CB; r += 256) {
    u64 kr2 = sel[r];
    int rk = 0;
    for (int j = 0; j < CB; ++j) rk += (sel[j] > kr2) ? 1 : 0;
    if (rk < PERCLS) selSorted[rk] = kr2;
  }
  __syncthreads();

  if (tid < PERCLS) {
    u64 key = selSorted[tid];
    float* o = out + tid * 6;
    if (key != 0ULL) {
      int wcls = 79 - (int)((key >> 11) & 0x7Fu);
      u32 pi = 2047u - (u32)(key & 0x7FFu);
      int wc = wcls + 1;
      // Re-gather + re-clip the winner's box (bitwise-identical clip).
      float4 b = clip_box(*(const float4*)(boxes + (size_t)pi * (NCLS * 4) + wc * 4));
      o[0] = b.x; o[1] = b.y; o[2] = b.z; o[3] = b.w;
      o[4] = funflip((u32)(key >> 32));
      o[5] = (float)wc;
    } else {
      // only reachable if fewer than 100 detections survive globally
      o[0] = 0.f; o[1] = 0.f; o[2] = 0.f; o[3] = 0.f; o[4] = NEGINF; o[5] = 0.f;
    }
  }
}

extern "C" void kernel_launch(void* const* d_in, const int* in_sizes, int n_in,
                              void* d_out, int out_size, void* d_ws, size_t ws_size,
                              hipStream_t stream) {
  const float* boxes  = (const float*)d_in[0];   // [2048, 324]
  const float* scores = (const float*)d_in[1];   // [2048, 81]
  char* ws = (char*)d_ws;
  u32*  gdone = (u32*)ws;                        // [0,64)
  u32*  cnt   = (u32*)(ws + 64);                 // [64, 5184)
  u32*  ghist = (u32*)(ws + 5184);               // [5184, 13376)
  u64*  keyws = (u64*)(ws + 13376);              // [13376, 126016)
  u64*  psarr = (u64*)(ws + 126016);             // [126016, 190016)
  float* out  = (float*)d_out;                   // [100, 6]

  hipMemsetAsync(ws, 0, 13376, stream);          // zero gdone + cnt + ghist
  scan_kernel<<<162, 256, 0, stream>>>((const float4*)scores, cnt, keyws);
  nms_topk_kernel<<<80, 256, 0, stream>>>(boxes, scores, cnt, keyws,
                                          psarr, ghist, gdone, out);
}